// Round 10
// baseline (457.385 us; speedup 1.0000x reference)
//
#include <hip/hip_runtime.h>
#include <hip/hip_bf16.h>

// ---------------------------------------------------------------------------
// ramsey_NN: node MLP (3 layers, train-mode BN) + all-pairs edge head.
// N=2048, F=64, H=128, C=2.  E = N(N-1)/2 = 2096128.
//
// R18 vs R17 (R17: fusion correct but gbar spun on atomicAdd(ctr,0) RMW ->
// 704 spinners serialized on one exclusive cacheline across 8 XCDs; k_edges
// 282us vs 136us of real work, k_nodes similar):
//   * ONE change: gbar spin = device-scope relaxed atomic LOAD (line stays
//     shared, no RMW ping-pong) + s_sleep(4) between polls. Arrive is still
//     a single atomicAdd. Fence protocol unchanged (R17-verified).
//   * Everything else byte-identical to R17 (which passed).
// ---------------------------------------------------------------------------

typedef short short8 __attribute__((ext_vector_type(8)));   // 8 x bf16
typedef float floatx4 __attribute__((ext_vector_type(4)));  // MFMA C/D
typedef float float2v __attribute__((ext_vector_type(2)));  // packed f32 pair

#define NN 2048
#define EPSV 1e-5f
#define EDGEF 2096128.f
#define EGRID 704   // edge blocks; x3 tiles = 2112

__device__ __forceinline__ float bf2f(short s) {
    return __uint_as_float(((unsigned)(unsigned short)s) << 16);
}
__device__ __forceinline__ short f2bf(float f) {   // RNE
    unsigned u = __float_as_uint(f);
    unsigned r = (u + 0x7FFFu + ((u >> 16) & 1u)) >> 16;
    return (short)r;
}
__device__ __forceinline__ float lrelu(float x) { return fmaxf(x, 0.01f * x); }

// pack two f32 -> one u32 of 2 bf16 (lo = a, hi = b)
__device__ __forceinline__ unsigned cvt_pk_bf16(float a, float b) {
    unsigned r;
    asm("v_cvt_pk_bf16_f32 %0, %1, %2" : "=v"(r) : "v"(a), "v"(b));
    return r;
}

// fragment-physical chunk index (16x16x32 bf16, A/B identity layout)
__device__ __forceinline__ int physB(int h, int f) {
    return ((((h >> 4) * 2 + (f >> 5)) * 64 + ((f >> 3) & 3) * 16 + (h & 15)) * 8) + (f & 7);
}

// pair-tile decode: i-groups of 16, j-tiles of 64, upper triangle.
// cum(q) = 130q - 2q^2 blocks before quad-group q. Tile ids 0..2111.
__device__ __forceinline__ void decode2(int bid, int& i0, int& j0, bool& str) {
    int q = (int)(0.25f * (130.f - sqrtf(16900.f - 8.f * (float)bid)));
    if (q < 0) q = 0;
    while (q > 0 && 130 * q - 2 * q * q > bid) --q;
    while (130 * (q + 1) - 2 * (q + 1) * (q + 1) <= bid) ++q;
    int r = bid - (130 * q - 2 * q * q);
    int n = 32 - q;
    int gs = (r >= n) + (r >= 2 * n) + (r >= 3 * n);
    int g = 4 * q + gs;
    int s = r - gs * n;
    i0 = g * 16;
    j0 = (q + s) * 64;
    str = (s == 0);
}

// device-scope spin barrier; ctr in memset-zeroed ws. All blocks co-resident
// by construction (k_nodes: 256 blocks = 1/CU; k_edges: 704 <= 3/CU*256).
// Arrive = one atomicAdd; spin = relaxed device-scope atomic LOAD (shared
// line, no RMW ping-pong) + s_sleep between polls.
__device__ __forceinline__ void gbar(int* ctr, int target) {
    __threadfence();
    __syncthreads();
    if (threadIdx.x == 0) {
        atomicAdd(ctr, 1);
        while (__hip_atomic_load(ctr, __ATOMIC_RELAXED,
                                 __HIP_MEMORY_SCOPE_AGENT) < target)
            __builtin_amdgcn_s_sleep(4);
    }
    __syncthreads();
    __threadfence();
}

// ---------------- fused node MLP: l1 -> bar -> l2 -> bar -> l3 ---------------
__global__ __launch_bounds__(256) void k_nodes(
    const float* __restrict__ nf,
    const float* __restrict__ W1, const float* __restrict__ b1,
    const float* __restrict__ g1, const float* __restrict__ be1,
    const float* __restrict__ W2, const float* __restrict__ b2,
    const float* __restrict__ g2, const float* __restrict__ be2,
    const float* __restrict__ W3, const float* __restrict__ b3,
    const float* __restrict__ W5,
    float* __restrict__ stat1, float* __restrict__ stat2,
    int* __restrict__ bars,
    short* __restrict__ w5bf, short* __restrict__ hb, float* __restrict__ hf)
{
    __shared__ float A[8 * 128];   // raw activations (layer outputs)
    __shared__ float B[8 * 128];   // x staging / normalized activations
    __shared__ float sS[128], sQ[128];
    int t = threadIdx.x, n0 = blockIdx.x * 8;

    if (blockIdx.x < 32) {                     // fused W5 -> bf16 frag-physical
        int idx = blockIdx.x * 256 + t;        // f*128+h over 8192
        w5bf[physB(idx & 127, idx >> 7)] = f2bf(W5[idx]);
    }

    // ---- layer 1 ----
    if (t < 128) { sS[t] = 0.f; sQ[t] = 0.f; }
    B[t] = nf[(size_t)n0 * 64 + t];
    B[t + 256] = nf[(size_t)n0 * 64 + t + 256];
    __syncthreads();
    int nl = t >> 5, h0 = (t & 31) * 4;
    {
        float acc[4];
        for (int k = 0; k < 4; ++k) acc[k] = b1[h0 + k];
        for (int f = 0; f < 64; ++f) {
            float r = B[nl * 64 + f];
            const float* wr = W1 + f * 128 + h0;
            for (int k = 0; k < 4; ++k) acc[k] = fmaf(r, wr[k], acc[k]);
        }
        for (int k = 0; k < 4; ++k) {
            float a = lrelu(acc[k]);
            A[nl * 128 + h0 + k] = a;
            atomicAdd(&sS[h0 + k], a);
            atomicAdd(&sQ[h0 + k], a * a);
        }
    }
    __syncthreads();
    if (t < 128) atomicAdd(&stat1[t], sS[t]);
    else atomicAdd(&stat1[t], sQ[t - 128]);

    gbar(bars + 0, 256);

    // ---- layer 2 ----
    if (t < 128) { sS[t] = 0.f; sQ[t] = 0.f; }
    for (int k = 0; k < 4; ++k) {
        int e = t + 256 * k;
        int h = e & 127;
        float m = stat1[h] * (1.f / 2048.f);
        float v = stat1[128 + h] * (1.f / 2048.f) - m * m;
        float sc = rsqrtf(v + EPSV);
        B[e] = (A[e] - m) * sc * g1[h] + be1[h];
    }
    __syncthreads();
    {
        float acc[4];
        for (int k = 0; k < 4; ++k) acc[k] = b2[h0 + k];
        for (int hi = 0; hi < 128; ++hi) {
            float r = B[nl * 128 + hi];
            const float* wr = W2 + hi * 128 + h0;
            for (int k = 0; k < 4; ++k) acc[k] = fmaf(r, wr[k], acc[k]);
        }
        __syncthreads();   // all reads of A (layer-1) done -> safe to overwrite
        for (int k = 0; k < 4; ++k) {
            float a = lrelu(acc[k]);
            A[nl * 128 + h0 + k] = a;
            atomicAdd(&sS[h0 + k], a);
            atomicAdd(&sQ[h0 + k], a * a);
        }
    }
    __syncthreads();
    if (t < 128) atomicAdd(&stat2[t], sS[t]);
    else atomicAdd(&stat2[t], sQ[t - 128]);

    gbar(bars + 1, 256);

    // ---- layer 3 + residual -> hb (bf16), hf (f32) ----
    for (int k = 0; k < 4; ++k) {
        int e = t + 256 * k;
        int h = e & 127;
        float m = stat2[h] * (1.f / 2048.f);
        float v = stat2[128 + h] * (1.f / 2048.f) - m * m;
        float sc = rsqrtf(v + EPSV);
        B[e] = (A[e] - m) * sc * g2[h] + be2[h];
    }
    __syncthreads();
    {
        int f0 = (t & 31) * 2;
        float acc0 = 0.f, acc1 = 0.f;
        for (int hi = 0; hi < 128; ++hi) {
            float r = B[nl * 128 + hi];
            const float* wr = W3 + hi * 64 + f0;
            acc0 = fmaf(r, wr[0], acc0);
            acc1 = fmaf(r, wr[1], acc1);
        }
        float v0 = acc0 + b3[f0] + nf[(size_t)(n0 + nl) * 64 + f0];
        float v1 = acc1 + b3[f0 + 1] + nf[(size_t)(n0 + nl) * 64 + f0 + 1];
        unsigned p = (unsigned)(unsigned short)f2bf(v0) |
                     ((unsigned)(unsigned short)f2bf(v1) << 16);
        ((unsigned*)hb)[(size_t)(n0 + nl) * 32 + (f0 >> 1)] = p;
        hf[(size_t)(n0 + nl) * 64 + f0] = v0;
        hf[(size_t)(n0 + nl) * 64 + f0 + 1] = v1;
    }
}

// ---------------- fused edge head: p1 (stats) -> bar -> fold -> p2 -----------
__global__ __launch_bounds__(256, 3) void k_edges(
    const short* __restrict__ hb, const float* __restrict__ hf,
    const short* __restrict__ w5bf, const float* __restrict__ b5,
    float* __restrict__ SQe8, const float* __restrict__ W6,
    const float* __restrict__ b6, const float* __restrict__ g5,
    const float* __restrict__ be5, int* __restrict__ bars,
    float* __restrict__ out)
{
    __shared__ __align__(16) float hi[16 * 64];   // 4 KB
    __shared__ __align__(16) short w5s[8192];     // 16 KB
    __shared__ __align__(16) float sw6[128];
    __shared__ float sred[2];
    __shared__ float sp[16][65];                  // probs, padded

    int t = threadIdx.x, lane = t & 63, w = t >> 6;
    int quad = lane >> 4, col = lane & 15;

    // stage w5 once per block (shared by all phases/tiles)
#pragma unroll
    for (int k = 0; k < 4; ++k)
        ((float4*)w5s)[t + 256 * k] = ((const float4*)w5bf)[t + 256 * k];
    const short* w5w = w5s + (size_t)lane * 8;    // +n*1024, +512 for ks=1
    floatx4 zero4 = {0.f, 0.f, 0.f, 0.f};

    // ================= phase 1: BN stats =================
    {
        float b5v[8];
#pragma unroll
        for (int n = 0; n < 8; ++n) b5v[n] = b5[n * 16 + col];
        float S[8], Q[8];
#pragma unroll
        for (int n = 0; n < 8; ++n) { S[n] = 0.f; Q[n] = 0.f; }

#pragma unroll 1
        for (int tile = blockIdx.x; tile < 2112; tile += EGRID) {
            int i0, j0; bool str;
            decode2(tile, i0, j0, str);
            __syncthreads();   // protect hi overwrite
            ((float4*)hi)[t] = ((const float4*)(hf + (size_t)i0 * 64))[t];
            float hjf[2][8];
#pragma unroll
            for (int ks = 0; ks < 2; ++ks) {
                short8 hv = *(const short8*)(hb + (size_t)(j0 + w * 16 + col) * 64 + ks * 32 + quad * 8);
#pragma unroll
                for (int e = 0; e < 8; ++e) hjf[ks][e] = bf2f(hv[e]);
            }
            __syncthreads();

            auto mkfrag = [&](int il, short8 (&af)[2]) {
#pragma unroll
                for (int ks = 0; ks < 2; ++ks) {
                    const float* hp = &hi[il * 64 + ks * 32 + quad * 8];
                    float4 h0 = *(const float4*)hp;
                    float4 h1 = *(const float4*)(hp + 4);
                    int4 aw;
                    aw.x = cvt_pk_bf16(h0.x * hjf[ks][0], h0.y * hjf[ks][1]);
                    aw.y = cvt_pk_bf16(h0.z * hjf[ks][2], h0.w * hjf[ks][3]);
                    aw.z = cvt_pk_bf16(h1.x * hjf[ks][4], h1.y * hjf[ks][5]);
                    aw.w = cvt_pk_bf16(h1.z * hjf[ks][6], h1.w * hjf[ks][7]);
                    af[ks] = *(short8*)&aw;
                }
            };

            if (!str) {
#pragma unroll 2
                for (int il = 0; il < 16; ++il) {
                    short8 af[2];
                    mkfrag(il, af);
#pragma unroll
                    for (int n = 0; n < 8; ++n) {
                        short8 wv0 = *(const short8*)(w5w + n * 1024);
                        short8 wv1 = *(const short8*)(w5w + n * 1024 + 512);
                        floatx4 c = __builtin_amdgcn_mfma_f32_16x16x32_bf16(af[0], wv0, zero4, 0, 0, 0);
                        c = __builtin_amdgcn_mfma_f32_16x16x32_bf16(af[1], wv1, c, 0, 0, 0);
                        float b = b5v[n];
#pragma unroll
                        for (int r = 0; r < 4; ++r) {
                            float a = lrelu(c[r] + b);
                            S[n] += a;
                            Q[n] = fmaf(a, a, Q[n]);
                        }
                    }
                }
            } else {
                int jgb = j0 + w * 16 + quad * 4;
#pragma unroll 2
                for (int il = 0; il < 16; ++il) {
                    short8 af[2];
                    mkfrag(il, af);
                    int ig = i0 + il;
#pragma unroll
                    for (int n = 0; n < 8; ++n) {
                        short8 wv0 = *(const short8*)(w5w + n * 1024);
                        short8 wv1 = *(const short8*)(w5w + n * 1024 + 512);
                        floatx4 c = __builtin_amdgcn_mfma_f32_16x16x32_bf16(af[0], wv0, zero4, 0, 0, 0);
                        c = __builtin_amdgcn_mfma_f32_16x16x32_bf16(af[1], wv1, c, 0, 0, 0);
                        float b = b5v[n];
#pragma unroll
                        for (int r = 0; r < 4; ++r) {
                            float a = (jgb + r > ig) ? lrelu(c[r] + b) : 0.f;
                            S[n] += a;
                            Q[n] = fmaf(a, a, Q[n]);
                        }
                    }
                }
            }
        }

        // flush stats once per block (8 spread copies to cut contention)
        float* dst = SQe8 + (blockIdx.x & 7) * 256;
#pragma unroll
        for (int n = 0; n < 8; ++n) {
            float Sa = S[n], Qa = Q[n];
            Sa += __shfl_xor(Sa, 16); Sa += __shfl_xor(Sa, 32);
            Qa += __shfl_xor(Qa, 16); Qa += __shfl_xor(Qa, 32);
            if (quad == 0) {
                atomicAdd(&dst[n * 16 + col], Sa);
                atomicAdd(&dst[128 + n * 16 + col], Qa);
            }
        }
    }

    gbar(bars, EGRID);

    // ================= fold (k_mid, per block) =================
    {
        float partv = 0.f;
        if (t < 128) {
            float s = 0.f, q = 0.f;
#pragma unroll
            for (int x = 0; x < 8; ++x) {
                s += SQe8[x * 256 + t];
                q += SQe8[x * 256 + 128 + t];
            }
            float m = s * (1.f / EDGEF);
            float v = q * (1.f / EDGEF) - m * m;
            float sc = rsqrtf(v + EPSV);
            float dW = W6[t * 2] - W6[t * 2 + 1];
            float sg = sc * g5[t];
            sw6[t] = sg * dW;
            partv = (be5[t] - m * sg) * dW;
        }
#pragma unroll
        for (int d = 1; d < 64; d <<= 1) partv += __shfl_xor(partv, d);
        if (t < 128 && lane == 0) sred[w] = partv;
    }
    __syncthreads();

    // ================= phase 2: probabilities =================
    {
        float bb = b6[0] - b6[1] + sred[0] + sred[1];
        floatx4 b5q4[8], w6q4[8];
#pragma unroll
        for (int n = 0; n < 8; ++n) {
            b5q4[n] = *(const floatx4*)(b5 + n * 16 + quad * 4);
            w6q4[n] = *(const floatx4*)&sw6[n * 16 + quad * 4];
        }

#pragma unroll 1
        for (int tile = blockIdx.x; tile < 2112; tile += EGRID) {
            int i0, j0; bool str;
            decode2(tile, i0, j0, str);
            __syncthreads();   // protect hi/sp overwrite
            ((float4*)hi)[t] = ((const float4*)(hf + (size_t)i0 * 64))[t];
            float hjf[2][8];
#pragma unroll
            for (int ks = 0; ks < 2; ++ks) {
                short8 hv = *(const short8*)(hb + (size_t)(j0 + w * 16 + col) * 64 + ks * 32 + quad * 8);
#pragma unroll
                for (int e = 0; e < 8; ++e) hjf[ks][e] = bf2f(hv[e]);
            }
            __syncthreads();

            auto mkfrag = [&](int il, short8 (&af)[2]) {
#pragma unroll
                for (int ks = 0; ks < 2; ++ks) {
                    const float* hp = &hi[il * 64 + ks * 32 + quad * 8];
                    float4 h0 = *(const float4*)hp;
                    float4 h1 = *(const float4*)(hp + 4);
                    int4 aw;
                    aw.x = cvt_pk_bf16(h0.x * hjf[ks][0], h0.y * hjf[ks][1]);
                    aw.y = cvt_pk_bf16(h0.z * hjf[ks][2], h0.w * hjf[ks][3]);
                    aw.z = cvt_pk_bf16(h1.x * hjf[ks][4], h1.y * hjf[ks][5]);
                    aw.w = cvt_pk_bf16(h1.z * hjf[ks][6], h1.w * hjf[ks][7]);
                    af[ks] = *(short8*)&aw;
                }
            };

#pragma unroll 2
            for (int il = 0; il < 16; ++il) {
                short8 af[2];
                mkfrag(il, af);
                float va[4] = {0.f, 0.f, 0.f, 0.f};
#pragma unroll
                for (int n = 0; n < 8; ++n) {
                    short8 wv0 = *(const short8*)(w5w + n * 1024);
                    short8 wv1 = *(const short8*)(w5w + n * 1024 + 512);
                    floatx4 c = __builtin_amdgcn_mfma_f32_16x16x32_bf16(wv0, af[0], zero4, 0, 0, 0);
                    c = __builtin_amdgcn_mfma_f32_16x16x32_bf16(wv1, af[1], c, 0, 0, 0);
#pragma unroll
                    for (int r = 0; r < 4; ++r)
                        va[r] = fmaf(lrelu(c[r] + ((const float*)&b5q4[n])[r]),
                                     ((const float*)&w6q4[n])[r], va[r]);
                }
                float v = (va[0] + va[1]) + (va[2] + va[3]);
                v += __shfl_xor(v, 16);
                v += __shfl_xor(v, 32);
                v += bb;
                float p = 1.f / (1.f + __expf(-v));
                if (quad == 0) sp[il][w * 16 + col] = p;
            }
            __syncthreads();

            if (!str) {
                int il2 = t >> 4, jb = (t & 15) * 4;
                float* op = out + ((size_t)(i0 + il2) * NN + j0 + jb) * 2;
#pragma unroll
                for (int q2 = 0; q2 < 2; ++q2) {
                    float p0 = sp[il2][jb + q2 * 2], p1 = sp[il2][jb + q2 * 2 + 1];
                    float4 u; u.x = p0; u.y = 1.f - p0; u.z = p1; u.w = 1.f - p1;
                    *(float4*)(op + q2 * 4) = u;
                }
                int jl = t >> 2, ib = (t & 3) * 4;
                float* om = out + ((size_t)(j0 + jl) * NN + i0 + ib) * 2;
#pragma unroll
                for (int q2 = 0; q2 < 2; ++q2) {
                    float p0 = sp[ib + q2 * 2][jl], p1 = sp[ib + q2 * 2 + 1][jl];
                    float4 u; u.x = p0; u.y = 1.f - p0; u.z = p1; u.w = 1.f - p1;
                    *(float4*)(om + q2 * 4) = u;
                }
            } else {
                int il2 = t >> 4, jb = (t & 15) * 4;
                int ig = i0 + il2;
#pragma unroll
                for (int e = 0; e < 4; ++e) {
                    int jg = j0 + jb + e;
                    if (jg > ig) {
                        float p = sp[il2][jb + e];
                        float2v pr; pr.x = p; pr.y = 1.f - p;
                        *(float2v*)(out + ((size_t)ig * NN + jg) * 2) = pr;
                    } else if (jg == ig) {
                        float2v pr; pr.x = 0.f; pr.y = 0.f;
                        *(float2v*)(out + ((size_t)ig * NN + jg) * 2) = pr;
                    }
                }
                int jl = t >> 2, ib = (t & 3) * 4;
                int jg = j0 + jl;
#pragma unroll
                for (int e = 0; e < 4; ++e) {
                    int ig2 = i0 + ib + e;
                    if (jg > ig2) {
                        float p = sp[ib + e][jl];
                        float2v pr; pr.x = p; pr.y = 1.f - p;
                        *(float2v*)(out + ((size_t)jg * NN + ig2) * 2) = pr;
                    }
                }
            }
        }
    }
}

// ---------------------------------------------------------------------------
extern "C" void kernel_launch(void* const* d_in, const int* in_sizes, int n_in,
                              void* d_out, int out_size, void* d_ws, size_t ws_size,
                              hipStream_t stream) {
    const float* nf  = (const float*)d_in[1];   // d_in[0]=x unused (ref ignores it)
    const float* W1  = (const float*)d_in[2];
    const float* b1  = (const float*)d_in[3];
    const float* g1  = (const float*)d_in[4];
    const float* be1 = (const float*)d_in[5];
    const float* W2  = (const float*)d_in[6];
    const float* b2  = (const float*)d_in[7];
    const float* g2  = (const float*)d_in[8];
    const float* be2 = (const float*)d_in[9];
    const float* W3  = (const float*)d_in[10];
    const float* b3  = (const float*)d_in[11];
    const float* W5  = (const float*)d_in[12];
    const float* b5  = (const float*)d_in[13];
    const float* g5  = (const float*)d_in[14];
    const float* be5 = (const float*)d_in[15];
    const float* W6  = (const float*)d_in[16];
    const float* b6  = (const float*)d_in[17];
    float* out = (float*)d_out;

    float* wsf   = (float*)d_ws;
    float* stat1 = wsf;                 // 256
    float* stat2 = wsf + 256;           // 256
    float* SQe8  = wsf + 512;           // 8*256 = 2048 (8 spread copies)
    int*   bars  = (int*)(wsf + 2560);  // 4 counters (zeroed by memset)
    float* act1  = wsf + 4096;          // (unused scratch region start)
    short* hb    = (short*)(act1 + 524288);   // 131072 bf16
    short* w5bf  = hb + 131072;               // 8192 bf16
    float* hf    = (float*)(w5bf + 8192);     // 131072 f32

    hipMemsetAsync(d_ws, 0, 4096 * sizeof(float), stream);

    k_nodes<<<256, 256, 0, stream>>>(nf, W1, b1, g1, be1, W2, b2, g2, be2,
                                     W3, b3, W5, stat1, stat2, bars,
                                     w5bf, hb, hf);
    k_edges<<<EGRID, 256, 0, stream>>>(hb, hf, w5bf, b5, SQe8, W6, b6, g5,
                                       be5, bars + 2, out);
}

// Round 12
// 238.853 us; speedup vs baseline: 1.9149x; 1.9149x over previous
//
#include <hip/hip_runtime.h>
#include <hip/hip_bf16.h>

// ---------------------------------------------------------------------------
// ramsey_NN: node MLP (3 layers, train-mode BN) + all-pairs edge head.
// N=2048, F=64, H=128, C=2.  E = N(N-1)/2 = 2096128.
//
// R20 = R14 (verified 243.2us best) + launch trimming WITHOUT barriers:
//   * R19 post-mortem: fence-free device barrier is UNSOUND (NaN: partially
//     visible stats); correct fences cost more than the launch overhead they
//     save. Persistent fusion abandoned.
//   * memset launch removed: node BN stats = per-block partials (plain
//     stores, no zero needed) + redundant coalesced reduction in consumer
//     (k_l1 -> pstat1 -> k_l2; k_l2 -> pstat2 -> k_l3). SQe8 zeroed by
//     k_l1 block 32 (ordered by kernel boundaries before edge_p1).
//   * edge_p1/edge_p2 byte-identical to R14.
//   * 5 launches: k_l1, k_l2, k_l3, edge_p1, edge_p2.
// ---------------------------------------------------------------------------

typedef short short8 __attribute__((ext_vector_type(8)));   // 8 x bf16
typedef float floatx4 __attribute__((ext_vector_type(4)));  // MFMA C/D
typedef float float2v __attribute__((ext_vector_type(2)));  // packed f32 pair

#define NN 2048
#define EPSV 1e-5f
#define EDGEF 2096128.f

__device__ __forceinline__ float bf2f(short s) {
    return __uint_as_float(((unsigned)(unsigned short)s) << 16);
}
__device__ __forceinline__ short f2bf(float f) {   // RNE
    unsigned u = __float_as_uint(f);
    unsigned r = (u + 0x7FFFu + ((u >> 16) & 1u)) >> 16;
    return (short)r;
}
__device__ __forceinline__ float lrelu(float x) { return fmaxf(x, 0.01f * x); }

// pack two f32 -> one u32 of 2 bf16 (lo = a, hi = b)
__device__ __forceinline__ unsigned cvt_pk_bf16(float a, float b) {
    unsigned r;
    asm("v_cvt_pk_bf16_f32 %0, %1, %2" : "=v"(r) : "v"(a), "v"(b));
    return r;
}

// fragment-physical chunk index (16x16x32 bf16, A/B identity layout)
__device__ __forceinline__ int physB(int h, int f) {
    return ((((h >> 4) * 2 + (f >> 5)) * 64 + ((f >> 3) & 3) * 16 + (h & 15)) * 8) + (f & 7);
}

// pair-tile decode: i-groups of 16, j-tiles of 64, upper triangle.
// cum(q) = 130q - 2q^2 blocks before quad-group q. Grid = 2112.
__device__ __forceinline__ void decode2(int bid, int& i0, int& j0, bool& str) {
    int q = (int)(0.25f * (130.f - sqrtf(16900.f - 8.f * (float)bid)));
    if (q < 0) q = 0;
    while (q > 0 && 130 * q - 2 * q * q > bid) --q;
    while (130 * (q + 1) - 2 * (q + 1) * (q + 1) <= bid) ++q;
    int r = bid - (130 * q - 2 * q * q);
    int n = 32 - q;
    int gs = (r >= n) + (r >= 2 * n) + (r >= 3 * n);
    int g = 4 * q + gs;
    int s = r - gs * n;
    i0 = g * 16;
    j0 = (q + s) * 64;
    str = (s == 0);
}

// ---------------- node layer 1: partials out (+ W5 conv, + SQe8 zero) -------
__global__ __launch_bounds__(256) void k_l1(const float* __restrict__ nf,
                                            const float* __restrict__ W1,
                                            const float* __restrict__ b1,
                                            const float* __restrict__ W5,
                                            float* __restrict__ act1,
                                            float* __restrict__ pstat1,
                                            float* __restrict__ SQe8,
                                            short* __restrict__ w5bf) {
    __shared__ float xl[8 * 64];
    __shared__ float sS[128], sQ[128];
    int t = threadIdx.x, n0 = blockIdx.x * 8;
    if (blockIdx.x < 32) {                     // fused W5 -> bf16 frag-physical
        int idx = blockIdx.x * 256 + t;        // f*128+h over 8192
        w5bf[physB(idx & 127, idx >> 7)] = f2bf(W5[idx]);
    }
    if (blockIdx.x == 32) {                    // zero SQe8 for edge_p1 atomics
#pragma unroll
        for (int k = 0; k < 8; ++k) SQe8[t + 256 * k] = 0.f;
    }
    if (t < 128) { sS[t] = 0.f; sQ[t] = 0.f; }
    xl[t] = nf[(size_t)n0 * 64 + t];
    xl[t + 256] = nf[(size_t)n0 * 64 + t + 256];
    __syncthreads();
    int nl = t >> 5, h0 = (t & 31) * 4;
    float acc[4];
    for (int k = 0; k < 4; ++k) acc[k] = b1[h0 + k];
    for (int f = 0; f < 64; ++f) {
        float r = xl[nl * 64 + f];
        const float* wr = W1 + f * 128 + h0;
        for (int k = 0; k < 4; ++k) acc[k] = fmaf(r, wr[k], acc[k]);
    }
    for (int k = 0; k < 4; ++k) {
        float a = lrelu(acc[k]);
        act1[(size_t)(n0 + nl) * 128 + h0 + k] = a;
        atomicAdd(&sS[h0 + k], a);
        atomicAdd(&sQ[h0 + k], a * a);
    }
    __syncthreads();
    // per-block partial (plain store; no zero/atomics needed)
    pstat1[blockIdx.x * 256 + t] = (t < 128) ? sS[t] : sQ[t - 128];
}

// ---------------- node layer 2: reduce pstat1, partials out ------------------
__global__ __launch_bounds__(256) void k_l2(const float* __restrict__ act1,
                                            const float* __restrict__ pstat1,
                                            const float* __restrict__ g1,
                                            const float* __restrict__ be1,
                                            const float* __restrict__ W2,
                                            const float* __restrict__ b2,
                                            float* __restrict__ act2,
                                            float* __restrict__ pstat2) {
    __shared__ float a1n[8 * 128];
    __shared__ float st[256];        // reduced stats: S[0:128], Q[128:256]
    __shared__ float sS[128], sQ[128];
    int t = threadIdx.x, n0 = blockIdx.x * 8;
    // redundant per-block reduction of 256 partials (coalesced rows)
    {
        float a0 = 0.f, a1 = 0.f, a2 = 0.f, a3 = 0.f;
#pragma unroll 4
        for (int b = 0; b < 256; b += 4) {
            a0 += pstat1[(b + 0) * 256 + t];
            a1 += pstat1[(b + 1) * 256 + t];
            a2 += pstat1[(b + 2) * 256 + t];
            a3 += pstat1[(b + 3) * 256 + t];
        }
        st[t] = (a0 + a1) + (a2 + a3);
    }
    if (t < 128) { sS[t] = 0.f; sQ[t] = 0.f; }
    __syncthreads();
    for (int k = 0; k < 4; ++k) {
        int e = t + 256 * k;
        int nl = e >> 7, h = e & 127;
        float m = st[h] * (1.f / 2048.f);
        float v = st[128 + h] * (1.f / 2048.f) - m * m;
        float sc = rsqrtf(v + EPSV);
        a1n[e] = (act1[(size_t)(n0 + nl) * 128 + h] - m) * sc * g1[h] + be1[h];
    }
    __syncthreads();
    int nl = t >> 5, h0 = (t & 31) * 4;
    float acc[4];
    for (int k = 0; k < 4; ++k) acc[k] = b2[h0 + k];
    for (int hi = 0; hi < 128; ++hi) {
        float r = a1n[nl * 128 + hi];
        const float* wr = W2 + hi * 128 + h0;
        for (int k = 0; k < 4; ++k) acc[k] = fmaf(r, wr[k], acc[k]);
    }
    for (int k = 0; k < 4; ++k) {
        float a = lrelu(acc[k]);
        act2[(size_t)(n0 + nl) * 128 + h0 + k] = a;
        atomicAdd(&sS[h0 + k], a);
        atomicAdd(&sQ[h0 + k], a * a);
    }
    __syncthreads();
    pstat2[blockIdx.x * 256 + t] = (t < 128) ? sS[t] : sQ[t - 128];
}

// ---------------- node layer 3: reduce pstat2; residual -> hb/hf -------------
__global__ __launch_bounds__(256) void k_l3(const float* __restrict__ act2,
                                            const float* __restrict__ pstat2,
                                            const float* __restrict__ g2,
                                            const float* __restrict__ be2,
                                            const float* __restrict__ W3,
                                            const float* __restrict__ b3,
                                            const float* __restrict__ nf,
                                            short* __restrict__ hb,
                                            float* __restrict__ hf) {
    __shared__ float a2n[8 * 128];
    __shared__ float st[256];
    int t = threadIdx.x, n0 = blockIdx.x * 8;
    {
        float a0 = 0.f, a1 = 0.f, a2 = 0.f, a3 = 0.f;
#pragma unroll 4
        for (int b = 0; b < 256; b += 4) {
            a0 += pstat2[(b + 0) * 256 + t];
            a1 += pstat2[(b + 1) * 256 + t];
            a2 += pstat2[(b + 2) * 256 + t];
            a3 += pstat2[(b + 3) * 256 + t];
        }
        st[t] = (a0 + a1) + (a2 + a3);
    }
    __syncthreads();
    for (int k = 0; k < 4; ++k) {
        int e = t + 256 * k;
        int nl = e >> 7, h = e & 127;
        float m = st[h] * (1.f / 2048.f);
        float v = st[128 + h] * (1.f / 2048.f) - m * m;
        float sc = rsqrtf(v + EPSV);
        a2n[e] = (act2[(size_t)(n0 + nl) * 128 + h] - m) * sc * g2[h] + be2[h];
    }
    __syncthreads();
    int nl = t >> 5, f0 = (t & 31) * 2;
    float acc[2] = {0.f, 0.f};
    for (int hi = 0; hi < 128; ++hi) {
        float r = a2n[nl * 128 + hi];
        const float* wr = W3 + hi * 64 + f0;
        acc[0] = fmaf(r, wr[0], acc[0]);
        acc[1] = fmaf(r, wr[1], acc[1]);
    }
    float v0 = acc[0] + b3[f0] + nf[(size_t)(n0 + nl) * 64 + f0];
    float v1 = acc[1] + b3[f0 + 1] + nf[(size_t)(n0 + nl) * 64 + f0 + 1];
    unsigned p = (unsigned)(unsigned short)f2bf(v0) |
                 ((unsigned)(unsigned short)f2bf(v1) << 16);
    ((unsigned*)hb)[(size_t)(n0 + nl) * 32 + (f0 >> 1)] = p;
    hf[(size_t)(n0 + nl) * 64 + f0] = v0;
    hf[(size_t)(n0 + nl) * 64 + f0 + 1] = v1;
}

// ---------------- edge pass 1: BN stats (pair-tile, T-free) ------------------
// R14-exact body: zero C-init, bias added post-MFMA (spill-free).
__global__ __launch_bounds__(256, 3) void edge_p1(
    const short* __restrict__ hb, const float* __restrict__ hf,
    const short* __restrict__ w5bf, const float* __restrict__ b5,
    float* __restrict__ SQe8)
{
    __shared__ __align__(16) float hi[16 * 64];   // 4 KB, f32 h_i rows
    int i0, j0; bool str;
    decode2(blockIdx.x, i0, j0, str);
    int t = threadIdx.x, lane = t & 63, w = t >> 6;
    int quad = lane >> 4, col = lane & 15;

    // stage h_i (16 rows x 64 f32) -- one float4 per thread
    ((float4*)hi)[t] = ((const float4*)(hf + (size_t)i0 * 64))[t];

    // h_j fragment (wave's 16 rows), unpacked to f32 (= bf16<<16, exact)
    float hjf[2][8];
#pragma unroll
    for (int ks = 0; ks < 2; ++ks) {
        short8 hv = *(const short8*)(hb + (size_t)(j0 + w * 16 + col) * 64 + ks * 32 + quad * 8);
#pragma unroll
        for (int e = 0; e < 8; ++e) hjf[ks][e] = bf2f(hv[e]);
    }
    // W5 fragments: all 128 h (frag-physical chunks (n*2+ks)*64+lane)
    short8 w5f[8][2];
#pragma unroll
    for (int n = 0; n < 8; ++n)
#pragma unroll
        for (int ks = 0; ks < 2; ++ks)
            w5f[n][ks] = ((const short8*)w5bf)[(n * 2 + ks) * 64 + lane];
    float b5v[8];
#pragma unroll
    for (int n = 0; n < 8; ++n) b5v[n] = b5[n * 16 + col];

    float S[8], Q[8];
#pragma unroll
    for (int n = 0; n < 8; ++n) { S[n] = 0.f; Q[n] = 0.f; }
    floatx4 zero4 = {0.f, 0.f, 0.f, 0.f};

    __syncthreads();

    auto mkfrag = [&](int il, short8 (&af)[2]) {
#pragma unroll
        for (int ks = 0; ks < 2; ++ks) {
            const float* hp = &hi[il * 64 + ks * 32 + quad * 8];
            float4 h0 = *(const float4*)hp;
            float4 h1 = *(const float4*)(hp + 4);
            int4 aw;
            aw.x = cvt_pk_bf16(h0.x * hjf[ks][0], h0.y * hjf[ks][1]);
            aw.y = cvt_pk_bf16(h0.z * hjf[ks][2], h0.w * hjf[ks][3]);
            aw.z = cvt_pk_bf16(h1.x * hjf[ks][4], h1.y * hjf[ks][5]);
            aw.w = cvt_pk_bf16(h1.z * hjf[ks][6], h1.w * hjf[ks][7]);
            af[ks] = *(short8*)&aw;
        }
    };

    if (!str) {
#pragma unroll 2
        for (int il = 0; il < 16; ++il) {
            short8 af[2];
            mkfrag(il, af);
#pragma unroll
            for (int n = 0; n < 8; ++n) {
                floatx4 c = __builtin_amdgcn_mfma_f32_16x16x32_bf16(af[0], w5f[n][0], zero4, 0, 0, 0);
                c = __builtin_amdgcn_mfma_f32_16x16x32_bf16(af[1], w5f[n][1], c, 0, 0, 0);
                float b = b5v[n];
#pragma unroll
                for (int r = 0; r < 4; ++r) {
                    float a = lrelu(c[r] + b);
                    S[n] += a;
                    Q[n] = fmaf(a, a, Q[n]);
                }
            }
        }
    } else {
        int jgb = j0 + w * 16 + quad * 4;
#pragma unroll 2
        for (int il = 0; il < 16; ++il) {
            short8 af[2];
            mkfrag(il, af);
            int ig = i0 + il;
#pragma unroll
            for (int n = 0; n < 8; ++n) {
                floatx4 c = __builtin_amdgcn_mfma_f32_16x16x32_bf16(af[0], w5f[n][0], zero4, 0, 0, 0);
                c = __builtin_amdgcn_mfma_f32_16x16x32_bf16(af[1], w5f[n][1], c, 0, 0, 0);
                float b = b5v[n];
#pragma unroll
                for (int r = 0; r < 4; ++r) {
                    float a = (jgb + r > ig) ? lrelu(c[r] + b) : 0.f;
                    S[n] += a;
                    Q[n] = fmaf(a, a, Q[n]);
                }
            }
        }
    }

    float* dst = SQe8 + (blockIdx.x & 7) * 256;
#pragma unroll
    for (int n = 0; n < 8; ++n) {
        float Sa = S[n], Qa = Q[n];
        Sa += __shfl_xor(Sa, 16); Sa += __shfl_xor(Sa, 32);
        Qa += __shfl_xor(Qa, 16); Qa += __shfl_xor(Qa, 32);
        if (quad == 0) {
            atomicAdd(&dst[n * 16 + col], Sa);
            atomicAdd(&dst[128 + n * 16 + col], Qa);
        }
    }
}

// ---------------- edge pass 2: fold (k_mid) + probabilities + symm write ----
// Swapped MFMA orientation (D rows = h): h-reduction in-register.
// Zero C-init; b5 added in epilogue (spill rule).
__global__ __launch_bounds__(256, 3) void edge_p2(
    const short* __restrict__ hb, const float* __restrict__ hf,
    const short* __restrict__ w5bf, const float* __restrict__ b5,
    const float* __restrict__ SQe8, const float* __restrict__ W6,
    const float* __restrict__ b6, const float* __restrict__ g5,
    const float* __restrict__ be5, float* __restrict__ out)
{
    __shared__ __align__(16) float hi[16 * 64];   // 4 KB
    __shared__ __align__(16) float sw6[128];      // folded w6d
    __shared__ float sred[2];
    __shared__ float sp[16][65];                  // probs, padded
    int i0, j0; bool str;
    decode2(blockIdx.x, i0, j0, str);
    int t = threadIdx.x, lane = t & 63, w = t >> 6;
    int quad = lane >> 4, col = lane & 15;

    ((float4*)hi)[t] = ((const float4*)(hf + (size_t)i0 * 64))[t];

    // ---- k_mid fold, redundant per block (~1us): sw6[h], bb ----
    float partv = 0.f;
    if (t < 128) {
        float s = 0.f, q = 0.f;
#pragma unroll
        for (int x = 0; x < 8; ++x) {
            s += SQe8[x * 256 + t];
            q += SQe8[x * 256 + 128 + t];
        }
        float m = s * (1.f / EDGEF);
        float v = q * (1.f / EDGEF) - m * m;
        float sc = rsqrtf(v + EPSV);
        float dW = W6[t * 2] - W6[t * 2 + 1];
        float sg = sc * g5[t];
        sw6[t] = sg * dW;
        partv = (be5[t] - m * sg) * dW;
    }
#pragma unroll
    for (int d = 1; d < 64; d <<= 1) partv += __shfl_xor(partv, d);
    if (t < 128 && lane == 0) sred[w] = partv;

    // h_j fragment (wave's 16 cols)
    float hjf[2][8];
#pragma unroll
    for (int ks = 0; ks < 2; ++ks) {
        short8 hv = *(const short8*)(hb + (size_t)(j0 + w * 16 + col) * 64 + ks * 32 + quad * 8);
#pragma unroll
        for (int e = 0; e < 8; ++e) hjf[ks][e] = bf2f(hv[e]);
    }
    short8 w5f[8][2];
#pragma unroll
    for (int n = 0; n < 8; ++n)
#pragma unroll
        for (int ks = 0; ks < 2; ++ks)
            w5f[n][ks] = ((const short8*)w5bf)[(n * 2 + ks) * 64 + lane];
    // per-(n,quad,r) bias: h = n*16 + quad*4 + r (D-row layout)
    floatx4 b5q4[8];
#pragma unroll
    for (int n = 0; n < 8; ++n)
        b5q4[n] = *(const floatx4*)(b5 + n * 16 + quad * 4);

    __syncthreads();   // hi, sw6, sred ready
    float bb = b6[0] - b6[1] + sred[0] + sred[1];
    floatx4 w6q4[8];
#pragma unroll
    for (int n = 0; n < 8; ++n)
        w6q4[n] = *(const floatx4*)&sw6[n * 16 + quad * 4];
    floatx4 zero4 = {0.f, 0.f, 0.f, 0.f};

    auto mkfrag = [&](int il, short8 (&af)[2]) {
#pragma unroll
        for (int ks = 0; ks < 2; ++ks) {
            const float* hp = &hi[il * 64 + ks * 32 + quad * 8];
            float4 h0 = *(const float4*)hp;
            float4 h1 = *(const float4*)(hp + 4);
            int4 aw;
            aw.x = cvt_pk_bf16(h0.x * hjf[ks][0], h0.y * hjf[ks][1]);
            aw.y = cvt_pk_bf16(h0.z * hjf[ks][2], h0.w * hjf[ks][3]);
            aw.z = cvt_pk_bf16(h1.x * hjf[ks][4], h1.y * hjf[ks][5]);
            aw.w = cvt_pk_bf16(h1.z * hjf[ks][6], h1.w * hjf[ks][7]);
            af[ks] = *(short8*)&aw;
        }
    };

#pragma unroll 2
    for (int il = 0; il < 16; ++il) {
        short8 af[2];
        mkfrag(il, af);
        float va[4] = {0.f, 0.f, 0.f, 0.f};
#pragma unroll
        for (int n = 0; n < 8; ++n) {
            floatx4 c = __builtin_amdgcn_mfma_f32_16x16x32_bf16(w5f[n][0], af[0], zero4, 0, 0, 0);
            c = __builtin_amdgcn_mfma_f32_16x16x32_bf16(w5f[n][1], af[1], c, 0, 0, 0);
#pragma unroll
            for (int r = 0; r < 4; ++r)
                va[r] = fmaf(lrelu(c[r] + ((const float*)&b5q4[n])[r]),
                             ((const float*)&w6q4[n])[r], va[r]);
        }
        float v = (va[0] + va[1]) + (va[2] + va[3]);
        v += __shfl_xor(v, 16);
        v += __shfl_xor(v, 32);
        v += bb;
        float p = 1.f / (1.f + __expf(-v));
        if (quad == 0) sp[il][w * 16 + col] = p;
    }
    __syncthreads();

    if (!str) {
        // forward: 16 rows x 64 pairs x 2 floats (coalesced float4)
        int il = t >> 4, jb = (t & 15) * 4;
        float* op = out + ((size_t)(i0 + il) * NN + j0 + jb) * 2;
#pragma unroll
        for (int q2 = 0; q2 < 2; ++q2) {
            float p0 = sp[il][jb + q2 * 2], p1 = sp[il][jb + q2 * 2 + 1];
            float4 u; u.x = p0; u.y = 1.f - p0; u.z = p1; u.w = 1.f - p1;
            *(float4*)(op + q2 * 4) = u;
        }
        // mirror: 64 rows x 16 x 2
        int jl = t >> 2, ib = (t & 3) * 4;
        float* om = out + ((size_t)(j0 + jl) * NN + i0 + ib) * 2;
#pragma unroll
        for (int q2 = 0; q2 < 2; ++q2) {
            float p0 = sp[ib + q2 * 2][jl], p1 = sp[ib + q2 * 2 + 1][jl];
            float4 u; u.x = p0; u.y = 1.f - p0; u.z = p1; u.w = 1.f - p1;
            *(float4*)(om + q2 * 4) = u;
        }
    } else {
        int il = t >> 4, jb = (t & 15) * 4;
        int ig = i0 + il;
#pragma unroll
        for (int e = 0; e < 4; ++e) {
            int jg = j0 + jb + e;
            if (jg > ig) {
                float p = sp[il][jb + e];
                float2v pr; pr.x = p; pr.y = 1.f - p;
                *(float2v*)(out + ((size_t)ig * NN + jg) * 2) = pr;
            } else if (jg == ig) {
                float2v pr; pr.x = 0.f; pr.y = 0.f;
                *(float2v*)(out + ((size_t)ig * NN + jg) * 2) = pr;
            }
        }
        int jl = t >> 2, ib = (t & 3) * 4;
        int jg = j0 + jl;
#pragma unroll
        for (int e = 0; e < 4; ++e) {
            int ig2 = i0 + ib + e;
            if (jg > ig2) {
                float p = sp[ib + e][jl];
                float2v pr; pr.x = p; pr.y = 1.f - p;
                *(float2v*)(out + ((size_t)jg * NN + ig2) * 2) = pr;
            }
        }
    }
}

// ---------------------------------------------------------------------------
extern "C" void kernel_launch(void* const* d_in, const int* in_sizes, int n_in,
                              void* d_out, int out_size, void* d_ws, size_t ws_size,
                              hipStream_t stream) {
    const float* nf  = (const float*)d_in[1];   // d_in[0]=x unused (ref ignores it)
    const float* W1  = (const float*)d_in[2];
    const float* b1  = (const float*)d_in[3];
    const float* g1  = (const float*)d_in[4];
    const float* be1 = (const float*)d_in[5];
    const float* W2  = (const float*)d_in[6];
    const float* b2  = (const float*)d_in[7];
    const float* g2  = (const float*)d_in[8];
    const float* be2 = (const float*)d_in[9];
    const float* W3  = (const float*)d_in[10];
    const float* b3  = (const float*)d_in[11];
    const float* W5  = (const float*)d_in[12];
    const float* b5  = (const float*)d_in[13];
    const float* g5  = (const float*)d_in[14];
    const float* be5 = (const float*)d_in[15];
    const float* W6  = (const float*)d_in[16];
    const float* b6  = (const float*)d_in[17];
    float* out = (float*)d_out;

    float* wsf    = (float*)d_ws;
    float* SQe8   = wsf;                 // 2048 (zeroed by k_l1 block 32)
    float* pstat1 = wsf + 2048;          // 256*256 = 65536
    float* pstat2 = pstat1 + 65536;      // 65536
    float* act1   = pstat2 + 65536;      // 262144
    float* act2   = act1 + 262144;       // 262144
    short* hb     = (short*)(act2 + 262144);   // 131072 bf16
    short* w5bf   = hb + 131072;               // 8192 bf16
    float* hf     = (float*)(w5bf + 8192);     // 131072 f32

    k_l1<<<256, 256, 0, stream>>>(nf, W1, b1, W5, act1, pstat1, SQe8, w5bf);
    k_l2<<<256, 256, 0, stream>>>(act1, pstat1, g1, be1, W2, b2, act2, pstat2);
    k_l3<<<256, 256, 0, stream>>>(act2, pstat2, g2, be2, W3, b3, nf, hb, hf);

    edge_p1<<<2112, 256, 0, stream>>>(hb, hf, w5bf, b5, SQe8);
    edge_p2<<<2112, 256, 0, stream>>>(hb, hf, w5bf, b5, SQe8, W6, b6, g5, be5, out);
}